// Round 17
// baseline (1854.508 us; speedup 1.0000x reference)
//
#include <hip/hip_runtime.h>

// ---------------------------------------------------------------------------
// GPT-style forward for MI355X (gfx950).
// L=6, E=1024, H=16, HD=64, T=1024, B=4, V=32000.  All matmuls in bf16 MFMA
// (16x16x32), accumulate f32.  Residual stream x in bf16.
// ---------------------------------------------------------------------------

typedef __bf16 bf16;
typedef __attribute__((ext_vector_type(8))) __bf16 bf16x8;
typedef __attribute__((ext_vector_type(4))) __bf16 bf16x4;
typedef __attribute__((ext_vector_type(4))) float  f32x4;

#define LAYERS 6
#define EMB    1024
#define HEADS  16
#define HDIM   64
#define SEQ    1024
#define BATCH  4
#define VOCAB  32000
#define ROWS   (BATCH * SEQ)   // 4096

#define AS1(p) ((__attribute__((address_space(1))) void*)(p))
#define AS3(p) ((__attribute__((address_space(3))) void*)(p))

// ---------------------------------------------------------------------------
// Weight transpose + f32 -> bf16.  in: [K][N] f32 row-major, out: [N][K] bf16.
// ---------------------------------------------------------------------------
__global__ void transpose_cvt(const float* __restrict__ in, bf16* __restrict__ out,
                              int K, int N)
{
    __shared__ float tile[32][33];
    int n0 = blockIdx.x * 32, k0 = blockIdx.y * 32;
    int tx = threadIdx.x, ty = threadIdx.y;           // (32, 8)
#pragma unroll
    for (int r = 0; r < 4; ++r)
        tile[ty + 8 * r][tx] = in[(size_t)(k0 + ty + 8 * r) * N + n0 + tx];
    __syncthreads();
#pragma unroll
    for (int r = 0; r < 4; ++r)
        out[(size_t)(n0 + ty + 8 * r) * K + k0 + tx] = (bf16)tile[tx][ty + 8 * r];
}

// ---------------------------------------------------------------------------
// ALL weight transposes for ALL 6 layers in ONE launch (73728 blocks).
// Per layer (12288 blocks): 0..4095 Wq/Wk/Wv/Wo, 4096..8191 W1, 8192.. W2.
// Outputs are per-layer slabs (lay * per-matrix stride).
// ---------------------------------------------------------------------------
__global__ void transpose_all6(const float* __restrict__ Wq, const float* __restrict__ Wk,
                               const float* __restrict__ Wv, const float* __restrict__ Wo,
                               const float* __restrict__ W1, const float* __restrict__ W2,
                               bf16* __restrict__ Tqkv, bf16* __restrict__ To,
                               bf16* __restrict__ T1, bf16* __restrict__ T2)
{
    __shared__ float tile[32][33];
    int tx = threadIdx.x, ty = threadIdx.y;           // (32, 8)
    int lay = blockIdx.x / 12288;
    int id  = blockIdx.x % 12288;
    const size_t wqs = (size_t)lay * 1024 * 1024;     // f32 elems per 1024x1024
    const size_t w14 = (size_t)lay * 4096 * 1024;
    const float* in; bf16* out; int K, N, n0, k0;
    if (id < 4096) {
        int z = id >> 10, rem = id & 1023;
        int bx = rem & 31, by = rem >> 5;
        K = 1024; N = 1024; n0 = bx * 32; k0 = by * 32;
        bf16* Tq = Tqkv + (size_t)lay * 3072 * 1024;
        switch (z) {
            case 0: in = Wq + wqs; out = Tq; break;
            case 1: in = Wk + wqs; out = Tq + (size_t)1024 * 1024; break;
            case 2: in = Wv + wqs; out = Tq + (size_t)2048 * 1024; break;
            default: in = Wo + wqs; out = To + (size_t)lay * 1024 * 1024; break;
        }
    } else if (id < 8192) {
        int rem = id - 4096;
        int bx = rem & 127, by = rem >> 7;
        in = W1 + w14; out = T1 + (size_t)lay * 4096 * 1024;
        K = 1024; N = 4096; n0 = bx * 32; k0 = by * 32;
    } else {
        int rem = id - 8192;
        int bx = rem & 127, by = rem >> 7;
        in = W2 + w14; out = T2 + (size_t)lay * 4096 * 1024;
        K = 4096; N = 1024; n0 = by * 32; k0 = bx * 32;
    }
#pragma unroll
    for (int r = 0; r < 4; ++r)
        tile[ty + 8 * r][tx] = in[(size_t)(k0 + ty + 8 * r) * N + n0 + tx];
    __syncthreads();
#pragma unroll
    for (int r = 0; r < 4; ++r)
        out[(size_t)(n0 + ty + 8 * r) * K + k0 + tx] = (bf16)tile[tx][ty + 8 * r];
}

// ---------------------------------------------------------------------------
// Embedding: x[b,t,:] = tok[idx[b,t]] + pos[t]   (bf16 residual stream)
// ---------------------------------------------------------------------------
__global__ void embed_kernel(const int* __restrict__ idx, const float* __restrict__ tok,
                             const float* __restrict__ pos, bf16* __restrict__ x)
{
    int row = blockIdx.x;            // b*SEQ + t
    int t   = row & (SEQ - 1);
    int id  = idx[row];
    int e   = threadIdx.x;           // *4
    float4 a = ((const float4*)(tok + (size_t)id * EMB))[e];
    float4 p = ((const float4*)(pos + (size_t)t  * EMB))[e];
    bf16x4 o;
    o.x = (bf16)(a.x + p.x); o.y = (bf16)(a.y + p.y);
    o.z = (bf16)(a.z + p.z); o.w = (bf16)(a.w + p.w);
    *(bf16x4*)(x + (size_t)row * EMB + e * 4) = o;
}

// ---------------------------------------------------------------------------
// LayerNorm over E=1024, bf16 in -> bf16 out.  One row per 256-thread block.
// ---------------------------------------------------------------------------
__global__ __launch_bounds__(256)
void ln_kernel(const bf16* __restrict__ x, const float* __restrict__ g,
               const float* __restrict__ b, bf16* __restrict__ out)
{
    int row = blockIdx.x;
    int t = threadIdx.x;
    bf16x4 xv = *(const bf16x4*)(x + (size_t)row * EMB + t * 4);
    float4 v; v.x = (float)xv.x; v.y = (float)xv.y; v.z = (float)xv.z; v.w = (float)xv.w;
    float s1 = v.x + v.y + v.z + v.w;
    float s2 = v.x * v.x + v.y * v.y + v.z * v.z + v.w * v.w;
#pragma unroll
    for (int off = 32; off > 0; off >>= 1) {
        s1 += __shfl_down(s1, off);
        s2 += __shfl_down(s2, off);
    }
    __shared__ float l1[4], l2[4];
    int wave = t >> 6;
    if ((t & 63) == 0) { l1[wave] = s1; l2[wave] = s2; }
    __syncthreads();
    float tot1 = l1[0] + l1[1] + l1[2] + l1[3];
    float tot2 = l2[0] + l2[1] + l2[2] + l2[3];
    float mean = tot1 * (1.f / EMB);
    float var  = tot2 * (1.f / EMB) - mean * mean;
    float rstd = rsqrtf(var + 1e-5f);
    float4 gg = ((const float4*)g)[t];
    float4 bb = ((const float4*)b)[t];
    bf16x4 o;
    o.x = (bf16)((v.x - mean) * rstd * gg.x + bb.x);
    o.y = (bf16)((v.y - mean) * rstd * gg.y + bb.y);
    o.z = (bf16)((v.z - mean) * rstd * gg.z + bb.z);
    o.w = (bf16)((v.w - mean) * rstd * gg.w + bb.w);
    *(bf16x4*)(out + (size_t)row * EMB + t * 4) = o;
}

// ---------------------------------------------------------------------------
// Pipelined 256x256 GEMM, register-double-buffered 4-phase schedule
// (round-4 best-measured configuration; 16x16x32 frags, 0 bank conflicts).
// Used for W1 (256 blocks, MODE 2) and the LM head (2000 blocks, MODE 3).
// ---------------------------------------------------------------------------
template <int MODE>
__global__ __launch_bounds__(512, 1)
void gemm256_kernel(const bf16* __restrict__ A, const bf16* __restrict__ BT,
                    void* Cv, const float* __restrict__ bias,
                    int N, int K, int nbm, int nbn)
{
    __shared__ __align__(16) bf16 lds[2][2][256 * 64];   // [slot][A|B][r*64 + pos*8]
    const int tid  = threadIdx.x;
    const int wave = tid >> 6, lane = tid & 63;
    const int lo = lane & 15, hi = lane >> 4;
    const int wm = wave >> 2, wn = wave & 3;   // 2 x 4 waves

    // XCD-bijective swizzle (m204), m-index fastest within a chunk.
    const int nwg = nbm * nbn;
    const int q = nwg >> 3, rem = nwg & 7;
    const int xcd = blockIdx.x & 7, boff = blockIdx.x >> 3;
    const int swz = (xcd < rem ? xcd * (q + 1) : rem * (q + 1) + (xcd - rem) * q) + boff;
    const int m0 = (swz % nbm) * 256;
    const int n0 = (swz / nbm) * 256;

    f32x4 acc[8][4];
#pragma unroll
    for (int m = 0; m < 8; ++m)
#pragma unroll
        for (int n = 0; n < 4; ++n)
            acc[m][n] = (f32x4){0.f, 0.f, 0.f, 0.f};

    const int NT = K >> 6;   // K-tiles of 64

    auto stage_ht = [&](int t, int ht) {
        const int slot = t & 1;
        const int k0 = t << 6;
        const int ab = ht >> 1;
        const int rbase = (ht & 1) << 7;
        const bf16* src = ab ? BT : A;
        const int base0 = ab ? n0 : m0;
#pragma unroll
        for (int j = 0; j < 2; ++j) {
            int g  = j * 512 + tid;
            int r  = g >> 3;
            int cc = (g & 7) ^ (r & 7);
            __builtin_amdgcn_global_load_lds(
                AS1(src + (size_t)(base0 + rbase + r) * K + k0 + cc * 8),
                AS3((char*)&lds[slot][ab][rbase * 64] + (size_t)g * 16), 16, 0, 0);
        }
    };

    bf16x8 bcur[4][2], bnxt[4][2], ae[2][2], ao[2][2];

    auto lda = [&](int t, int mp, bf16x8 (&out)[2][2]) {
        const int slot = t & 1;
#pragma unroll
        for (int mi = 0; mi < 2; ++mi)
#pragma unroll
            for (int ks = 0; ks < 2; ++ks) {
                int r = wm * 128 + (mp * 2 + mi) * 16 + lo;
                int pos = (ks * 4 + hi) ^ (r & 7);
                out[mi][ks] = *(const bf16x8*)(&lds[slot][0][r * 64 + pos * 8]);
            }
    };
    auto ldb = [&](int t, bf16x8 (&out)[4][2]) {
        const int slot = t & 1;
#pragma unroll
        for (int n = 0; n < 4; ++n)
#pragma unroll
            for (int ks = 0; ks < 2; ++ks) {
                int r = wn * 64 + n * 16 + lo;
                int pos = (ks * 4 + hi) ^ (r & 7);
                out[n][ks] = *(const bf16x8*)(&lds[slot][1][r * 64 + pos * 8]);
            }
    };
    auto mfma16 = [&](int mp, bf16x8 (&a)[2][2]) {
        __builtin_amdgcn_s_setprio(1);
#pragma unroll
        for (int mi = 0; mi < 2; ++mi)
#pragma unroll
            for (int n = 0; n < 4; ++n)
#pragma unroll
                for (int ks = 0; ks < 2; ++ks)
                    acc[mp * 2 + mi][n] =
                        __builtin_amdgcn_mfma_f32_16x16x32_bf16(a[mi][ks], bcur[n][ks],
                                                                acc[mp * 2 + mi][n], 0, 0, 0);
        __builtin_amdgcn_s_setprio(0);
    };

    stage_ht(0, 0); stage_ht(0, 1); stage_ht(0, 2); stage_ht(0, 3);
    asm volatile("s_waitcnt vmcnt(0)\n\ts_barrier" ::: "memory");
    ldb(0, bcur);
    lda(0, 0, ae);

    for (int t = 0; t < NT; ++t) {
        const bool more = (t + 1 < NT);
        if (more) { stage_ht(t + 1, 0); stage_ht(t + 1, 1); }
        lda(t, 1, ao);
        mfma16(0, ae);
        if (more) { stage_ht(t + 1, 2); stage_ht(t + 1, 3); }
        lda(t, 2, ae);
        mfma16(1, ao);
        lda(t, 3, ao);
        mfma16(2, ae);
        if (more) {
            asm volatile("s_waitcnt vmcnt(0) lgkmcnt(0)\n\ts_barrier" ::: "memory");
            ldb(t + 1, bnxt);
            lda(t + 1, 0, ae);
        }
        mfma16(3, ao);
        if (more) {
#pragma unroll
            for (int n = 0; n < 4; ++n)
#pragma unroll
                for (int ks = 0; ks < 2; ++ks)
                    bcur[n][ks] = bnxt[n][ks];
        }
    }

#pragma unroll
    for (int m = 0; m < 8; ++m) {
        int row = m0 + wm * 128 + m * 16 + hi * 4;
#pragma unroll
        for (int n = 0; n < 4; ++n) {
            int col = n0 + wn * 64 + n * 16 + lo;
            float bv = (MODE != 0) ? bias[col] : 0.f;
#pragma unroll
            for (int j = 0; j < 4; ++j) {
                size_t o = (size_t)(row + j) * N + col;
                float v = acc[m][n][j] + bv;
                if (MODE == 2)      ((bf16*)Cv)[o]  = (bf16)fmaxf(v, 0.f);
                else if (MODE == 3) ((float*)Cv)[o] = v;
                else                ((bf16*)Cv)[o]  = (bf16)v;
            }
        }
    }
}

// ---------------------------------------------------------------------------
// 128x128 GEMM (m97-style).  Grid (N/128, M/128) -> 768 blocks for QKV.
// MODE 4: QKV fused V-transpose.
// ---------------------------------------------------------------------------
template <int MODE>
__global__ __launch_bounds__(256)
void gemm_kernel(const bf16* __restrict__ A, const bf16* __restrict__ BT,
                 void* Cv, const float* __restrict__ bias,
                 const bf16* __restrict__ resid, bf16* __restrict__ vt,
                 int N, int K)
{
    __shared__ __align__(16) bf16 As[128 * 64];
    __shared__ __align__(16) bf16 Bs[128 * 64];
    const int tid = threadIdx.x;
    const int wave = tid >> 6, lane = tid & 63;
    const int lo = lane & 15, hi = lane >> 4;
    const int wm = wave >> 1, wn = wave & 1;
    const int m0 = blockIdx.y * 128, n0 = blockIdx.x * 128;

    f32x4 acc[4][4];
#pragma unroll
    for (int m = 0; m < 4; ++m)
#pragma unroll
        for (int n = 0; n < 4; ++n)
            acc[m][n] = (f32x4){0.f, 0.f, 0.f, 0.f};

    const int sb = wave * 4;
    for (int k0 = 0; k0 < K; k0 += 64) {
#pragma unroll
        for (int i = 0; i < 4; ++i) {
            int g   = (sb + i) * 64 + lane;
            int row = g >> 3;
            int lc  = (g & 7) ^ (row & 7);
            const bf16* ga = A  + (size_t)(m0 + row) * K + k0 + lc * 8;
            const bf16* gb = BT + (size_t)(n0 + row) * K + k0 + lc * 8;
            __builtin_amdgcn_global_load_lds(AS1(ga), AS3(As + (sb + i) * 512), 16, 0, 0);
            __builtin_amdgcn_global_load_lds(AS1(gb), AS3(Bs + (sb + i) * 512), 16, 0, 0);
        }
        asm volatile("s_waitcnt vmcnt(0)" ::: "memory");
        __syncthreads();
#pragma unroll
        for (int ks = 0; ks < 2; ++ks) {
            bf16x8 af[4], bfr[4];
#pragma unroll
            for (int m = 0; m < 4; ++m) {
                int r  = wm * 64 + m * 16 + lo;
                int pc = (ks * 4 + hi) ^ (r & 7);
                af[m] = *(const bf16x8*)(As + r * 64 + pc * 8);
            }
#pragma unroll
            for (int n = 0; n < 4; ++n) {
                int r  = wn * 64 + n * 16 + lo;
                int pc = (ks * 4 + hi) ^ (r & 7);
                bfr[n] = *(const bf16x8*)(Bs + r * 64 + pc * 8);
            }
#pragma unroll
            for (int m = 0; m < 4; ++m)
#pragma unroll
                for (int n = 0; n < 4; ++n)
                    acc[m][n] = __builtin_amdgcn_mfma_f32_16x16x32_bf16(af[m], bfr[n], acc[m][n], 0, 0, 0);
        }
        __syncthreads();
    }

    if (MODE == 4 && n0 >= 2048) {
#pragma unroll
        for (int m = 0; m < 4; ++m) {
            int rowb = m0 + wm * 64 + m * 16 + hi * 4;
            int bb = rowb >> 10, t = rowb & 1023;
#pragma unroll
            for (int n = 0; n < 4; ++n) {
                int hd = n0 - 2048 + wn * 64 + n * 16 + lo;
                bf16x4 w;
                w.x = (bf16)acc[m][n][0]; w.y = (bf16)acc[m][n][1];
                w.z = (bf16)acc[m][n][2]; w.w = (bf16)acc[m][n][3];
                *(bf16x4*)(vt + ((size_t)(bb * 1024 + hd)) * SEQ + t) = w;
            }
        }
        return;
    }

#pragma unroll
    for (int m = 0; m < 4; ++m) {
        int rbase = m0 + wm * 64 + m * 16 + hi * 4;
#pragma unroll
        for (int n = 0; n < 4; ++n) {
            int col = n0 + wn * 64 + n * 16 + lo;
            float bv = (MODE == 1) ? bias[col] : 0.f;
#pragma unroll
            for (int j = 0; j < 4; ++j) {
                size_t off = (size_t)(rbase + j) * N + col;
                float v = acc[m][n][j] + bv;
                if (MODE == 1)      ((bf16*)Cv)[off] = (bf16)(v + (float)resid[off]);
                else                ((bf16*)Cv)[off] = (bf16)v;
            }
        }
    }
}

// ---------------------------------------------------------------------------
// 64x128 GEMM for small-B-panel narrow-N layers ONLY (Wo K=1024, W2 K=4096).
// MODE 1: bf16 out = acc + bias + resid(bf16).
// ---------------------------------------------------------------------------
template <int MODE>
__global__ __launch_bounds__(256)
void gemm64_kernel(const bf16* __restrict__ A, const bf16* __restrict__ BT,
                   bf16* __restrict__ C, const float* __restrict__ bias,
                   const bf16* __restrict__ resid, int N, int K)
{
    __shared__ __align__(16) bf16 As[64 * 64];
    __shared__ __align__(16) bf16 Bs[128 * 64];
    const int tid = threadIdx.x;
    const int wave = tid >> 6, lane = tid & 63;
    const int lo = lane & 15, hi = lane >> 4;
    const int wm = wave >> 1, wn = wave & 1;
    const int m0 = blockIdx.y * 64, n0 = blockIdx.x * 128;

    f32x4 acc[2][4];
#pragma unroll
    for (int m = 0; m < 2; ++m)
#pragma unroll
        for (int n = 0; n < 4; ++n)
            acc[m][n] = (f32x4){0.f, 0.f, 0.f, 0.f};

    for (int k0 = 0; k0 < K; k0 += 64) {
#pragma unroll
        for (int i = 0; i < 2; ++i) {
            int c   = i * 256 + tid;
            int row = c >> 3;
            int cc  = (c & 7) ^ (row & 7);
            __builtin_amdgcn_global_load_lds(
                AS1(A + (size_t)(m0 + row) * K + k0 + cc * 8),
                AS3(As + (size_t)c * 8), 16, 0, 0);
        }
#pragma unroll
        for (int i = 0; i < 4; ++i) {
            int c   = i * 256 + tid;
            int row = c >> 3;
            int cc  = (c & 7) ^ (row & 7);
            __builtin_amdgcn_global_load_lds(
                AS1(BT + (size_t)(n0 + row) * K + k0 + cc * 8),
                AS3(Bs + (size_t)c * 8), 16, 0, 0);
        }
        asm volatile("s_waitcnt vmcnt(0)" ::: "memory");
        __syncthreads();
#pragma unroll
        for (int ks = 0; ks < 2; ++ks) {
            bf16x8 af[2], bfr[4];
#pragma unroll
            for (int m = 0; m < 2; ++m) {
                int r  = wm * 32 + m * 16 + lo;
                int pc = (ks * 4 + hi) ^ (r & 7);
                af[m] = *(const bf16x8*)(As + r * 64 + pc * 8);
            }
#pragma unroll
            for (int n = 0; n < 4; ++n) {
                int r  = wn * 64 + n * 16 + lo;
                int pc = (ks * 4 + hi) ^ (r & 7);
                bfr[n] = *(const bf16x8*)(Bs + r * 64 + pc * 8);
            }
#pragma unroll
            for (int m = 0; m < 2; ++m)
#pragma unroll
                for (int n = 0; n < 4; ++n)
                    acc[m][n] = __builtin_amdgcn_mfma_f32_16x16x32_bf16(af[m], bfr[n], acc[m][n], 0, 0, 0);
        }
        __syncthreads();
    }

#pragma unroll
    for (int m = 0; m < 2; ++m) {
        int rbase = m0 + wm * 32 + m * 16 + hi * 4;
#pragma unroll
        for (int n = 0; n < 4; ++n) {
            int col = n0 + wn * 64 + n * 16 + lo;
            float bv = bias[col];
#pragma unroll
            for (int j = 0; j < 4; ++j) {
                size_t off = (size_t)(rbase + j) * N + col;
                float v = acc[m][n][j] + bv;
                if (MODE == 1) C[off] = (bf16)(v + (float)resid[off]);
                else           C[off] = (bf16)fmaxf(v, 0.f);
            }
        }
    }
}

// ---------------------------------------------------------------------------
// Fused causal attention: one wave owns 32 t-rows (two 16-row groups).
// No __syncthreads (1-wave block); V loads hoisted; exp2-domain softmax;
// defer-max (T13).  Dispatch REVERSED (largest t0 first) so the longest
// blocks start earliest and the tail packs under the short ones.
// ---------------------------------------------------------------------------
__global__ __launch_bounds__(64)
void attn_kernel(const bf16* __restrict__ qkv, const bf16* __restrict__ vt,
                 bf16* __restrict__ att)
{
    const float SC2 = 0.125f * 1.44269504089f;   // scale * log2(e)
    int bh = blockIdx.x; int b = bh >> 4, h = bh & 15;
    int t0 = (31 - (int)blockIdx.y) * 32;        // reversed: long blocks first
    int lane = threadIdx.x;
    int lo = lane & 15, hi = lane >> 4;
    const bf16* kb = qkv + (size_t)(b * SEQ) * 3072 + EMB + h * 64;  // k part
    const bf16* qb = qkv + (size_t)(b * SEQ) * 3072 + h * 64;        // q part
    const bf16* vb = vt + (size_t)bh * 64 * SEQ;                     // [64][SEQ]

    bf16x8 bK[2][2];
#pragma unroll
    for (int g = 0; g < 2; ++g) {
        bK[g][0] = *(const bf16x8*)(kb + (size_t)(t0 + g * 16 + lo) * 3072 + hi * 8);
        bK[g][1] = *(const bf16x8*)(kb + (size_t)(t0 + g * 16 + lo) * 3072 + 32 + hi * 8);
    }

    f32x4 o[2][4];
#pragma unroll
    for (int g = 0; g < 2; ++g)
#pragma unroll
        for (int n = 0; n < 4; ++n) o[g][n] = (f32x4){0.f, 0.f, 0.f, 0.f};
    float mrun[2] = {-1e30f, -1e30f}, lrun[2] = {0.f, 0.f};

    __shared__ __align__(16) bf16 plds[32][72];   // [t-local][s], pad 72

    const int nt = (t0 + 32 + 63) >> 6;                       // s-tiles (cover t0+32)
    const int nfull = (t0 >= 64) ? (((t0 - 63) >> 6) + 1) : 0; // fully-visible tiles

    auto tile_body = [&](int s0, bool masked) {
        // QK^T (swapped operands): D[s][t]
        f32x4 sc[2][4];
#pragma unroll
        for (int g = 0; g < 2; ++g)
#pragma unroll
            for (int sh = 0; sh < 4; ++sh) sc[g][sh] = (f32x4){0.f, 0.f, 0.f, 0.f};
#pragma unroll
        for (int sh = 0; sh < 4; ++sh) {
            const bf16* qr = qb + (size_t)(s0 + sh * 16 + lo) * 3072;
            bf16x8 aQ0 = *(const bf16x8*)(qr + hi * 8);
            bf16x8 aQ1 = *(const bf16x8*)(qr + 32 + hi * 8);
#pragma unroll
            for (int g = 0; g < 2; ++g) {
                sc[g][sh] = __builtin_amdgcn_mfma_f32_16x16x32_bf16(aQ0, bK[g][0], sc[g][sh], 0, 0, 0);
                sc[g][sh] = __builtin_amdgcn_mfma_f32_16x16x32_bf16(aQ1, bK[g][1], sc[g][sh], 0, 0, 0);
            }
        }
        // V loads issued EARLY: latency hides under the softmax VALU below.
        bf16x8 bV0[4], bV1[4];
#pragma unroll
        for (int n = 0; n < 4; ++n) {
            bV0[n] = *(const bf16x8*)(vb + (size_t)(n * 16 + lo) * SEQ + s0 + hi * 8);
            bV1[n] = *(const bf16x8*)(vb + (size_t)(n * 16 + lo) * SEQ + s0 + 32 + hi * 8);
        }
        // softmax in exp2 domain
        float p[2][16], mx[2];
#pragma unroll
        for (int g = 0; g < 2; ++g) {
            const int tt = t0 + g * 16 + lo;
            mx[g] = -1e30f;
#pragma unroll
            for (int sh = 0; sh < 4; ++sh)
#pragma unroll
                for (int j = 0; j < 4; ++j) {
                    float val = sc[g][sh][j] * SC2;
                    if (masked) {
                        int s = s0 + sh * 16 + hi * 4 + j;
                        if (s > tt) val = -1e30f;
                    }
                    p[g][sh * 4 + j] = val;
                    mx[g] = fmaxf(mx[g], val);
                }
            mx[g] = fmaxf(mx[g], __shfl_xor(mx[g], 16));
            mx[g] = fmaxf(mx[g], __shfl_xor(mx[g], 32));
        }
        // defer-max (T13), shared trigger, log2 domain (bound 2^8)
        if (__any(fmaxf(mx[0] - mrun[0], mx[1] - mrun[1]) > 8.f)) {
#pragma unroll
            for (int g = 0; g < 2; ++g) {
                float mnew = fmaxf(mrun[g], mx[g]);
                float scl = exp2f(mrun[g] - mnew);
                mrun[g] = mnew;
                lrun[g] *= scl;
                float sclj[4];
#pragma unroll
                for (int j = 0; j < 4; ++j) sclj[j] = __shfl(scl, hi * 4 + j);
#pragma unroll
                for (int n = 0; n < 4; ++n)
#pragma unroll
                    for (int j = 0; j < 4; ++j)
                        o[g][n][j] *= sclj[j];
            }
        }
#pragma unroll
        for (int g = 0; g < 2; ++g) {
            float rs = 0.f;
#pragma unroll
            for (int i = 0; i < 16; ++i) { p[g][i] = exp2f(p[g][i] - mrun[g]); rs += p[g][i]; }
            rs += __shfl_xor(rs, 16);
            rs += __shfl_xor(rs, 32);
            lrun[g] += rs;
        }
        // publish P (same-wave DS ordering; no barrier needed in 1-wave block)
#pragma unroll
        for (int g = 0; g < 2; ++g)
#pragma unroll
            for (int sh = 0; sh < 4; ++sh) {
                bf16x4 w;
                w.x = (bf16)p[g][sh * 4 + 0]; w.y = (bf16)p[g][sh * 4 + 1];
                w.z = (bf16)p[g][sh * 4 + 2]; w.w = (bf16)p[g][sh * 4 + 3];
                *(bf16x4*)(&plds[g * 16 + lo][sh * 16 + hi * 4]) = w;
            }
        bf16x8 aP[2][2];
#pragma unroll
        for (int g = 0; g < 2; ++g) {
            aP[g][0] = *(const bf16x8*)(&plds[g * 16 + lo][hi * 8]);
            aP[g][1] = *(const bf16x8*)(&plds[g * 16 + lo][32 + hi * 8]);
        }
#pragma unroll
        for (int n = 0; n < 4; ++n)
#pragma unroll
            for (int g = 0; g < 2; ++g) {
                o[g][n] = __builtin_amdgcn_mfma_f32_16x16x32_bf16(aP[g][0], bV0[n], o[g][n], 0, 0, 0);
                o[g][n] = __builtin_amdgcn_mfma_f32_16x16x32_bf16(aP[g][1], bV1[n], o[g][n], 0, 0, 0);
            }
    };

    for (int it = 0; it < nfull; ++it) tile_body(it * 64, false);
    for (int it = nfull; it < nt; ++it) tile_body(it * 64, true);

#pragma unroll
    for (int g = 0; g < 2; ++g) {
        float lj[4];
#pragma unroll
        for (int j = 0; j < 4; ++j) lj[j] = __shfl(lrun[g], hi * 4 + j);
#pragma unroll
        for (int j = 0; j < 4; ++j) {
            float inv = 1.f / lj[j];
            size_t rowoff = (size_t)(b * SEQ + t0 + g * 16 + hi * 4 + j) * EMB + h * 64;
#pragma unroll
            for (int n = 0; n < 4; ++n)
                att[rowoff + n * 16 + lo] = (bf16)(o[g][n][j] * inv);
        }
    }
}

// ---------------------------------------------------------------------------
extern "C" void kernel_launch(void* const* d_in, const int* in_sizes, int n_in,
                              void* d_out, int out_size, void* d_ws, size_t ws_size,
                              hipStream_t stream)
{
    const int*   idx  = (const int*)d_in[0];
    const float* tok  = (const float*)d_in[1];
    const float* pos  = (const float*)d_in[2];
    const float* Wq   = (const float*)d_in[3];
    const float* Wk   = (const float*)d_in[4];
    const float* Wv   = (const float*)d_in[5];
    const float* Wo   = (const float*)d_in[6];
    const float* bo   = (const float*)d_in[7];
    const float* W1   = (const float*)d_in[8];
    const float* b1   = (const float*)d_in[9];
    const float* W2   = (const float*)d_in[10];
    const float* b2   = (const float*)d_in[11];
    const float* ln1g = (const float*)d_in[12];
    const float* ln1b = (const float*)d_in[13];
    const float* ln2g = (const float*)d_in[14];
    const float* ln2b = (const float*)d_in[15];
    const float* lnfg = (const float*)d_in[16];
    const float* lnfb = (const float*)d_in[17];
    const float* Wlm  = (const float*)d_in[18];
    const float* blm  = (const float*)d_in[19];
    float* out = (float*)d_out;

    char* ws = (char*)d_ws;
    size_t off = 0;
    auto alloc = [&](size_t bytes) { void* p = ws + off; off += (bytes + 255) & ~(size_t)255; return p; };
    bf16* x     = (bf16*)alloc((size_t)ROWS * EMB * 2);      // bf16 residual stream
    bf16* h     = (bf16*)alloc((size_t)ROWS * EMB * 2);
    bf16* qkv   = (bf16*)alloc((size_t)ROWS * 3072 * 2);
    bf16* vt    = (bf16*)alloc((size_t)ROWS * EMB * 2);
    bf16* attb  = (bf16*)alloc((size_t)ROWS * EMB * 2);
    bf16* mlp   = (bf16*)alloc((size_t)ROWS * 4096 * 2);
    // per-layer weight slabs (all 6 layers transposed once up front)
    bf16* WTqkv = (bf16*)alloc((size_t)LAYERS * 3072 * 1024 * 2);
    bf16* WTo   = (bf16*)alloc((size_t)LAYERS * 1024 * 1024 * 2);
    bf16* WT1   = (bf16*)alloc((size_t)LAYERS * 4096 * 1024 * 2);
    bf16* WT2   = (bf16*)alloc((size_t)LAYERS * 1024 * 4096 * 2);
    bf16* WTlm  = (bf16*)alloc((size_t)VOCAB * 1024 * 2);

    dim3 tb(32, 8);

    // all weight transposes: LM head + ALL six layers in two launches
    transpose_cvt<<<dim3(VOCAB / 32, 32), tb, 0, stream>>>(Wlm, WTlm, 1024, VOCAB);
    transpose_all6<<<LAYERS * 12288, tb, 0, stream>>>(Wq, Wk, Wv, Wo, W1, W2,
                                                      WTqkv, WTo, WT1, WT2);

    embed_kernel<<<ROWS, 256, 0, stream>>>(idx, tok, pos, x);

    for (int l = 0; l < LAYERS; ++l) {
        bf16* Tq = WTqkv + (size_t)l * 3072 * 1024;
        bf16* To = WTo   + (size_t)l * 1024 * 1024;
        bf16* T1 = WT1   + (size_t)l * 4096 * 1024;
        bf16* T2 = WT2   + (size_t)l * 4096 * 1024;

        ln_kernel<<<ROWS, 256, 0, stream>>>(x, ln1g + l * EMB, ln1b + l * EMB, h);
        gemm_kernel<4><<<dim3(24, 32), 256, 0, stream>>>(h, Tq, qkv, nullptr, nullptr, vt, 3072, 1024);
        attn_kernel<<<dim3(64, 32), 64, 0, stream>>>(qkv, vt, attb);
        gemm64_kernel<1><<<dim3(8, 64), 256, 0, stream>>>(attb, To, x, bo + l * EMB, x, 1024, 1024);
        ln_kernel<<<ROWS, 256, 0, stream>>>(x, ln2g + l * EMB, ln2b + l * EMB, h);
        gemm256_kernel<2><<<16 * 16, 512, 0, stream>>>(h, T1, mlp, b1 + l * 4096, 4096, 1024, 16, 16);
        gemm64_kernel<1><<<dim3(8, 64), 256, 0, stream>>>(mlp, T2, x, b2 + l * EMB, x, 1024, 4096);
    }
    ln_kernel<<<ROWS, 256, 0, stream>>>(x, lnfg, lnfb, h);
    gemm256_kernel<3><<<16 * 125, 512, 0, stream>>>(h, WTlm, out, blm, 32000, 1024, 16, 125);
}

// Round 18
// 1724.543 us; speedup vs baseline: 1.0754x; 1.0754x over previous
//
#include <hip/hip_runtime.h>

// ---------------------------------------------------------------------------
// GPT-style forward for MI355X (gfx950).
// L=6, E=1024, H=16, HD=64, T=1024, B=4, V=32000.  All matmuls in bf16 MFMA
// (16x16x32), accumulate f32.  Residual stream x in bf16.
// ROUND 18: clean revert to the round-16 best-measured configuration.
// ---------------------------------------------------------------------------

typedef __bf16 bf16;
typedef __attribute__((ext_vector_type(8))) __bf16 bf16x8;
typedef __attribute__((ext_vector_type(4))) __bf16 bf16x4;
typedef __attribute__((ext_vector_type(4))) float  f32x4;

#define LAYERS 6
#define EMB    1024
#define HEADS  16
#define HDIM   64
#define SEQ    1024
#define BATCH  4
#define VOCAB  32000
#define ROWS   (BATCH * SEQ)   // 4096

#define AS1(p) ((__attribute__((address_space(1))) void*)(p))
#define AS3(p) ((__attribute__((address_space(3))) void*)(p))

// ---------------------------------------------------------------------------
// Weight transpose + f32 -> bf16.  in: [K][N] f32 row-major, out: [N][K] bf16.
// ---------------------------------------------------------------------------
__global__ void transpose_cvt(const float* __restrict__ in, bf16* __restrict__ out,
                              int K, int N)
{
    __shared__ float tile[32][33];
    int n0 = blockIdx.x * 32, k0 = blockIdx.y * 32;
    int tx = threadIdx.x, ty = threadIdx.y;           // (32, 8)
#pragma unroll
    for (int r = 0; r < 4; ++r)
        tile[ty + 8 * r][tx] = in[(size_t)(k0 + ty + 8 * r) * N + n0 + tx];
    __syncthreads();
#pragma unroll
    for (int r = 0; r < 4; ++r)
        out[(size_t)(n0 + ty + 8 * r) * K + k0 + tx] = (bf16)tile[tx][ty + 8 * r];
}

// ---------------------------------------------------------------------------
// All six per-layer weight transposes in ONE launch (12288 blocks, 1-D grid)
// — run per layer so the written slabs stay L2-warm for the GEMMs that
// immediately consume them (round-17 lesson: upfront all-layer transpose
// loses this temporal locality and regresses).
// ---------------------------------------------------------------------------
__global__ void transpose_all(const float* __restrict__ Wq, const float* __restrict__ Wk,
                              const float* __restrict__ Wv, const float* __restrict__ Wo,
                              const float* __restrict__ W1, const float* __restrict__ W2,
                              bf16* __restrict__ Tq, bf16* __restrict__ Tk,
                              bf16* __restrict__ Tv, bf16* __restrict__ To,
                              bf16* __restrict__ T1, bf16* __restrict__ T2)
{
    __shared__ float tile[32][33];
    int tx = threadIdx.x, ty = threadIdx.y;           // (32, 8)
    int id = blockIdx.x;
    const float* in; bf16* out; int K, N, n0, k0;
    if (id < 4096) {
        int z = id >> 10, rem = id & 1023;
        int bx = rem & 31, by = rem >> 5;
        K = 1024; N = 1024; n0 = bx * 32; k0 = by * 32;
        switch (z) {
            case 0: in = Wq; out = Tq; break;
            case 1: in = Wk; out = Tk; break;
            case 2: in = Wv; out = Tv; break;
            default: in = Wo; out = To; break;
        }
    } else if (id < 8192) {
        int rem = id - 4096;
        int bx = rem & 127, by = rem >> 7;
        in = W1; out = T1; K = 1024; N = 4096; n0 = bx * 32; k0 = by * 32;
    } else {
        int rem = id - 8192;
        int bx = rem & 127, by = rem >> 7;
        in = W2; out = T2; K = 4096; N = 1024; n0 = by * 32; k0 = bx * 32;
    }
#pragma unroll
    for (int r = 0; r < 4; ++r)
        tile[ty + 8 * r][tx] = in[(size_t)(k0 + ty + 8 * r) * N + n0 + tx];
    __syncthreads();
#pragma unroll
    for (int r = 0; r < 4; ++r)
        out[(size_t)(n0 + ty + 8 * r) * K + k0 + tx] = (bf16)tile[tx][ty + 8 * r];
}

// ---------------------------------------------------------------------------
// Embedding: x[b,t,:] = tok[idx[b,t]] + pos[t]   (bf16 residual stream)
// ---------------------------------------------------------------------------
__global__ void embed_kernel(const int* __restrict__ idx, const float* __restrict__ tok,
                             const float* __restrict__ pos, bf16* __restrict__ x)
{
    int row = blockIdx.x;            // b*SEQ + t
    int t   = row & (SEQ - 1);
    int id  = idx[row];
    int e   = threadIdx.x;           // *4
    float4 a = ((const float4*)(tok + (size_t)id * EMB))[e];
    float4 p = ((const float4*)(pos + (size_t)t  * EMB))[e];
    bf16x4 o;
    o.x = (bf16)(a.x + p.x); o.y = (bf16)(a.y + p.y);
    o.z = (bf16)(a.z + p.z); o.w = (bf16)(a.w + p.w);
    *(bf16x4*)(x + (size_t)row * EMB + e * 4) = o;
}

// ---------------------------------------------------------------------------
// LayerNorm over E=1024, bf16 in -> bf16 out.  One row per 256-thread block.
// ---------------------------------------------------------------------------
__global__ __launch_bounds__(256)
void ln_kernel(const bf16* __restrict__ x, const float* __restrict__ g,
               const float* __restrict__ b, bf16* __restrict__ out)
{
    int row = blockIdx.x;
    int t = threadIdx.x;
    bf16x4 xv = *(const bf16x4*)(x + (size_t)row * EMB + t * 4);
    float4 v; v.x = (float)xv.x; v.y = (float)xv.y; v.z = (float)xv.z; v.w = (float)xv.w;
    float s1 = v.x + v.y + v.z + v.w;
    float s2 = v.x * v.x + v.y * v.y + v.z * v.z + v.w * v.w;
#pragma unroll
    for (int off = 32; off > 0; off >>= 1) {
        s1 += __shfl_down(s1, off);
        s2 += __shfl_down(s2, off);
    }
    __shared__ float l1[4], l2[4];
    int wave = t >> 6;
    if ((t & 63) == 0) { l1[wave] = s1; l2[wave] = s2; }
    __syncthreads();
    float tot1 = l1[0] + l1[1] + l1[2] + l1[3];
    float tot2 = l2[0] + l2[1] + l2[2] + l2[3];
    float mean = tot1 * (1.f / EMB);
    float var  = tot2 * (1.f / EMB) - mean * mean;
    float rstd = rsqrtf(var + 1e-5f);
    float4 gg = ((const float4*)g)[t];
    float4 bb = ((const float4*)b)[t];
    bf16x4 o;
    o.x = (bf16)((v.x - mean) * rstd * gg.x + bb.x);
    o.y = (bf16)((v.y - mean) * rstd * gg.y + bb.y);
    o.z = (bf16)((v.z - mean) * rstd * gg.z + bb.z);
    o.w = (bf16)((v.w - mean) * rstd * gg.w + bb.w);
    *(bf16x4*)(out + (size_t)row * EMB + t * 4) = o;
}

// ---------------------------------------------------------------------------
// Pipelined 256x256 GEMM, register-double-buffered 4-phase schedule
// (round-4 best-measured configuration; 16x16x32 frags, 0 bank conflicts).
// Used for W1 (256 blocks, MODE 2) and the LM head (2000 blocks, MODE 3).
// ---------------------------------------------------------------------------
template <int MODE>
__global__ __launch_bounds__(512, 1)
void gemm256_kernel(const bf16* __restrict__ A, const bf16* __restrict__ BT,
                    void* Cv, const float* __restrict__ bias,
                    int N, int K, int nbm, int nbn)
{
    __shared__ __align__(16) bf16 lds[2][2][256 * 64];   // [slot][A|B][r*64 + pos*8]
    const int tid  = threadIdx.x;
    const int wave = tid >> 6, lane = tid & 63;
    const int lo = lane & 15, hi = lane >> 4;
    const int wm = wave >> 2, wn = wave & 3;   // 2 x 4 waves

    // XCD-bijective swizzle (m204), m-index fastest within a chunk.
    const int nwg = nbm * nbn;
    const int q = nwg >> 3, rem = nwg & 7;
    const int xcd = blockIdx.x & 7, boff = blockIdx.x >> 3;
    const int swz = (xcd < rem ? xcd * (q + 1) : rem * (q + 1) + (xcd - rem) * q) + boff;
    const int m0 = (swz % nbm) * 256;
    const int n0 = (swz / nbm) * 256;

    f32x4 acc[8][4];
#pragma unroll
    for (int m = 0; m < 8; ++m)
#pragma unroll
        for (int n = 0; n < 4; ++n)
            acc[m][n] = (f32x4){0.f, 0.f, 0.f, 0.f};

    const int NT = K >> 6;   // K-tiles of 64

    auto stage_ht = [&](int t, int ht) {
        const int slot = t & 1;
        const int k0 = t << 6;
        const int ab = ht >> 1;
        const int rbase = (ht & 1) << 7;
        const bf16* src = ab ? BT : A;
        const int base0 = ab ? n0 : m0;
#pragma unroll
        for (int j = 0; j < 2; ++j) {
            int g  = j * 512 + tid;
            int r  = g >> 3;
            int cc = (g & 7) ^ (r & 7);
            __builtin_amdgcn_global_load_lds(
                AS1(src + (size_t)(base0 + rbase + r) * K + k0 + cc * 8),
                AS3((char*)&lds[slot][ab][rbase * 64] + (size_t)g * 16), 16, 0, 0);
        }
    };

    bf16x8 bcur[4][2], bnxt[4][2], ae[2][2], ao[2][2];

    auto lda = [&](int t, int mp, bf16x8 (&out)[2][2]) {
        const int slot = t & 1;
#pragma unroll
        for (int mi = 0; mi < 2; ++mi)
#pragma unroll
            for (int ks = 0; ks < 2; ++ks) {
                int r = wm * 128 + (mp * 2 + mi) * 16 + lo;
                int pos = (ks * 4 + hi) ^ (r & 7);
                out[mi][ks] = *(const bf16x8*)(&lds[slot][0][r * 64 + pos * 8]);
            }
    };
    auto ldb = [&](int t, bf16x8 (&out)[4][2]) {
        const int slot = t & 1;
#pragma unroll
        for (int n = 0; n < 4; ++n)
#pragma unroll
            for (int ks = 0; ks < 2; ++ks) {
                int r = wn * 64 + n * 16 + lo;
                int pos = (ks * 4 + hi) ^ (r & 7);
                out[n][ks] = *(const bf16x8*)(&lds[slot][1][r * 64 + pos * 8]);
            }
    };
    auto mfma16 = [&](int mp, bf16x8 (&a)[2][2]) {
        __builtin_amdgcn_s_setprio(1);
#pragma unroll
        for (int mi = 0; mi < 2; ++mi)
#pragma unroll
            for (int n = 0; n < 4; ++n)
#pragma unroll
                for (int ks = 0; ks < 2; ++ks)
                    acc[mp * 2 + mi][n] =
                        __builtin_amdgcn_mfma_f32_16x16x32_bf16(a[mi][ks], bcur[n][ks],
                                                                acc[mp * 2 + mi][n], 0, 0, 0);
        __builtin_amdgcn_s_setprio(0);
    };

    stage_ht(0, 0); stage_ht(0, 1); stage_ht(0, 2); stage_ht(0, 3);
    asm volatile("s_waitcnt vmcnt(0)\n\ts_barrier" ::: "memory");
    ldb(0, bcur);
    lda(0, 0, ae);

    for (int t = 0; t < NT; ++t) {
        const bool more = (t + 1 < NT);
        if (more) { stage_ht(t + 1, 0); stage_ht(t + 1, 1); }
        lda(t, 1, ao);
        mfma16(0, ae);
        if (more) { stage_ht(t + 1, 2); stage_ht(t + 1, 3); }
        lda(t, 2, ae);
        mfma16(1, ao);
        lda(t, 3, ao);
        mfma16(2, ae);
        if (more) {
            asm volatile("s_waitcnt vmcnt(0) lgkmcnt(0)\n\ts_barrier" ::: "memory");
            ldb(t + 1, bnxt);
            lda(t + 1, 0, ae);
        }
        mfma16(3, ao);
        if (more) {
#pragma unroll
            for (int n = 0; n < 4; ++n)
#pragma unroll
                for (int ks = 0; ks < 2; ++ks)
                    bcur[n][ks] = bnxt[n][ks];
        }
    }

#pragma unroll
    for (int m = 0; m < 8; ++m) {
        int row = m0 + wm * 128 + m * 16 + hi * 4;
#pragma unroll
        for (int n = 0; n < 4; ++n) {
            int col = n0 + wn * 64 + n * 16 + lo;
            float bv = (MODE != 0) ? bias[col] : 0.f;
#pragma unroll
            for (int j = 0; j < 4; ++j) {
                size_t o = (size_t)(row + j) * N + col;
                float v = acc[m][n][j] + bv;
                if (MODE == 2)      ((bf16*)Cv)[o]  = (bf16)fmaxf(v, 0.f);
                else if (MODE == 3) ((float*)Cv)[o] = v;
                else                ((bf16*)Cv)[o]  = (bf16)v;
            }
        }
    }
}

// ---------------------------------------------------------------------------
// 128x128 GEMM (m97-style).  Grid (N/128, M/128) -> 768 blocks for QKV.
// MODE 4: QKV fused V-transpose.
// ---------------------------------------------------------------------------
template <int MODE>
__global__ __launch_bounds__(256)
void gemm_kernel(const bf16* __restrict__ A, const bf16* __restrict__ BT,
                 void* Cv, const float* __restrict__ bias,
                 const bf16* __restrict__ resid, bf16* __restrict__ vt,
                 int N, int K)
{
    __shared__ __align__(16) bf16 As[128 * 64];
    __shared__ __align__(16) bf16 Bs[128 * 64];
    const int tid = threadIdx.x;
    const int wave = tid >> 6, lane = tid & 63;
    const int lo = lane & 15, hi = lane >> 4;
    const int wm = wave >> 1, wn = wave & 1;
    const int m0 = blockIdx.y * 128, n0 = blockIdx.x * 128;

    f32x4 acc[4][4];
#pragma unroll
    for (int m = 0; m < 4; ++m)
#pragma unroll
        for (int n = 0; n < 4; ++n)
            acc[m][n] = (f32x4){0.f, 0.f, 0.f, 0.f};

    const int sb = wave * 4;
    for (int k0 = 0; k0 < K; k0 += 64) {
#pragma unroll
        for (int i = 0; i < 4; ++i) {
            int g   = (sb + i) * 64 + lane;
            int row = g >> 3;
            int lc  = (g & 7) ^ (row & 7);
            const bf16* ga = A  + (size_t)(m0 + row) * K + k0 + lc * 8;
            const bf16* gb = BT + (size_t)(n0 + row) * K + k0 + lc * 8;
            __builtin_amdgcn_global_load_lds(AS1(ga), AS3(As + (sb + i) * 512), 16, 0, 0);
            __builtin_amdgcn_global_load_lds(AS1(gb), AS3(Bs + (sb + i) * 512), 16, 0, 0);
        }
        asm volatile("s_waitcnt vmcnt(0)" ::: "memory");
        __syncthreads();
#pragma unroll
        for (int ks = 0; ks < 2; ++ks) {
            bf16x8 af[4], bfr[4];
#pragma unroll
            for (int m = 0; m < 4; ++m) {
                int r  = wm * 64 + m * 16 + lo;
                int pc = (ks * 4 + hi) ^ (r & 7);
                af[m] = *(const bf16x8*)(As + r * 64 + pc * 8);
            }
#pragma unroll
            for (int n = 0; n < 4; ++n) {
                int r  = wn * 64 + n * 16 + lo;
                int pc = (ks * 4 + hi) ^ (r & 7);
                bfr[n] = *(const bf16x8*)(Bs + r * 64 + pc * 8);
            }
#pragma unroll
            for (int m = 0; m < 4; ++m)
#pragma unroll
                for (int n = 0; n < 4; ++n)
                    acc[m][n] = __builtin_amdgcn_mfma_f32_16x16x32_bf16(af[m], bfr[n], acc[m][n], 0, 0, 0);
        }
        __syncthreads();
    }

    if (MODE == 4 && n0 >= 2048) {
#pragma unroll
        for (int m = 0; m < 4; ++m) {
            int rowb = m0 + wm * 64 + m * 16 + hi * 4;
            int bb = rowb >> 10, t = rowb & 1023;
#pragma unroll
            for (int n = 0; n < 4; ++n) {
                int hd = n0 - 2048 + wn * 64 + n * 16 + lo;
                bf16x4 w;
                w.x = (bf16)acc[m][n][0]; w.y = (bf16)acc[m][n][1];
                w.z = (bf16)acc[m][n][2]; w.w = (bf16)acc[m][n][3];
                *(bf16x4*)(vt + ((size_t)(bb * 1024 + hd)) * SEQ + t) = w;
            }
        }
        return;
    }

#pragma unroll
    for (int m = 0; m < 4; ++m) {
        int rbase = m0 + wm * 64 + m * 16 + hi * 4;
#pragma unroll
        for (int n = 0; n < 4; ++n) {
            int col = n0 + wn * 64 + n * 16 + lo;
            float bv = (MODE == 1) ? bias[col] : 0.f;
#pragma unroll
            for (int j = 0; j < 4; ++j) {
                size_t off = (size_t)(rbase + j) * N + col;
                float v = acc[m][n][j] + bv;
                if (MODE == 1)      ((bf16*)Cv)[off] = (bf16)(v + (float)resid[off]);
                else                ((bf16*)Cv)[off] = (bf16)v;
            }
        }
    }
}

// ---------------------------------------------------------------------------
// 64x128 GEMM for small-B-panel narrow-N layers ONLY (Wo K=1024, W2 K=4096).
// MODE 1: bf16 out = acc + bias + resid(bf16).
// ---------------------------------------------------------------------------
template <int MODE>
__global__ __launch_bounds__(256)
void gemm64_kernel(const bf16* __restrict__ A, const bf16* __restrict__ BT,
                   bf16* __restrict__ C, const float* __restrict__ bias,
                   const bf16* __restrict__ resid, int N, int K)
{
    __shared__ __align__(16) bf16 As[64 * 64];
    __shared__ __align__(16) bf16 Bs[128 * 64];
    const int tid = threadIdx.x;
    const int wave = tid >> 6, lane = tid & 63;
    const int lo = lane & 15, hi = lane >> 4;
    const int wm = wave >> 1, wn = wave & 1;
    const int m0 = blockIdx.y * 64, n0 = blockIdx.x * 128;

    f32x4 acc[2][4];
#pragma unroll
    for (int m = 0; m < 2; ++m)
#pragma unroll
        for (int n = 0; n < 4; ++n)
            acc[m][n] = (f32x4){0.f, 0.f, 0.f, 0.f};

    for (int k0 = 0; k0 < K; k0 += 64) {
#pragma unroll
        for (int i = 0; i < 2; ++i) {
            int c   = i * 256 + tid;
            int row = c >> 3;
            int cc  = (c & 7) ^ (row & 7);
            __builtin_amdgcn_global_load_lds(
                AS1(A + (size_t)(m0 + row) * K + k0 + cc * 8),
                AS3(As + (size_t)c * 8), 16, 0, 0);
        }
#pragma unroll
        for (int i = 0; i < 4; ++i) {
            int c   = i * 256 + tid;
            int row = c >> 3;
            int cc  = (c & 7) ^ (row & 7);
            __builtin_amdgcn_global_load_lds(
                AS1(BT + (size_t)(n0 + row) * K + k0 + cc * 8),
                AS3(Bs + (size_t)c * 8), 16, 0, 0);
        }
        asm volatile("s_waitcnt vmcnt(0)" ::: "memory");
        __syncthreads();
#pragma unroll
        for (int ks = 0; ks < 2; ++ks) {
            bf16x8 af[2], bfr[4];
#pragma unroll
            for (int m = 0; m < 2; ++m) {
                int r  = wm * 32 + m * 16 + lo;
                int pc = (ks * 4 + hi) ^ (r & 7);
                af[m] = *(const bf16x8*)(As + r * 64 + pc * 8);
            }
#pragma unroll
            for (int n = 0; n < 4; ++n) {
                int r  = wn * 64 + n * 16 + lo;
                int pc = (ks * 4 + hi) ^ (r & 7);
                bfr[n] = *(const bf16x8*)(Bs + r * 64 + pc * 8);
            }
#pragma unroll
            for (int m = 0; m < 2; ++m)
#pragma unroll
                for (int n = 0; n < 4; ++n)
                    acc[m][n] = __builtin_amdgcn_mfma_f32_16x16x32_bf16(af[m], bfr[n], acc[m][n], 0, 0, 0);
        }
        __syncthreads();
    }

#pragma unroll
    for (int m = 0; m < 2; ++m) {
        int rbase = m0 + wm * 32 + m * 16 + hi * 4;
#pragma unroll
        for (int n = 0; n < 4; ++n) {
            int col = n0 + wn * 64 + n * 16 + lo;
            float bv = bias[col];
#pragma unroll
            for (int j = 0; j < 4; ++j) {
                size_t off = (size_t)(rbase + j) * N + col;
                float v = acc[m][n][j] + bv;
                if (MODE == 1) C[off] = (bf16)(v + (float)resid[off]);
                else           C[off] = (bf16)fmaxf(v, 0.f);
            }
        }
    }
}

// ---------------------------------------------------------------------------
// Fused causal attention: one wave owns 32 t-rows (two 16-row groups).
// No __syncthreads (1-wave block; same-wave DS ops are processed in order by
// the LDS pipe, compiler inserts lgkm waits for the may-alias plds
// write->read) -> no vmcnt(0) drains -> Q/V loads overlap across tiles.
// V loads hoisted above the softmax; exp2-domain softmax; defer-max (T13).
// ---------------------------------------------------------------------------
__global__ __launch_bounds__(64)
void attn_kernel(const bf16* __restrict__ qkv, const bf16* __restrict__ vt,
                 bf16* __restrict__ att)
{
    const float SC2 = 0.125f * 1.44269504089f;   // scale * log2(e)
    int bh = blockIdx.x; int b = bh >> 4, h = bh & 15;
    int t0 = blockIdx.y * 32;
    int lane = threadIdx.x;
    int lo = lane & 15, hi = lane >> 4;
    const bf16* kb = qkv + (size_t)(b * SEQ) * 3072 + EMB + h * 64;  // k part
    const bf16* qb = qkv + (size_t)(b * SEQ) * 3072 + h * 64;        // q part
    const bf16* vb = vt + (size_t)bh * 64 * SEQ;                     // [64][SEQ]

    bf16x8 bK[2][2];
#pragma unroll
    for (int g = 0; g < 2; ++g) {
        bK[g][0] = *(const bf16x8*)(kb + (size_t)(t0 + g * 16 + lo) * 3072 + hi * 8);
        bK[g][1] = *(const bf16x8*)(kb + (size_t)(t0 + g * 16 + lo) * 3072 + 32 + hi * 8);
    }

    f32x4 o[2][4];
#pragma unroll
    for (int g = 0; g < 2; ++g)
#pragma unroll
        for (int n = 0; n < 4; ++n) o[g][n] = (f32x4){0.f, 0.f, 0.f, 0.f};
    float mrun[2] = {-1e30f, -1e30f}, lrun[2] = {0.f, 0.f};

    __shared__ __align__(16) bf16 plds[32][72];   // [t-local][s], pad 72

    const int nt = (t0 + 32 + 63) >> 6;                       // s-tiles (cover t0+32)
    const int nfull = (t0 >= 64) ? (((t0 - 63) >> 6) + 1) : 0; // fully-visible tiles

    auto tile_body = [&](int s0, bool masked) {
        // QK^T (swapped operands): D[s][t]
        f32x4 sc[2][4];
#pragma unroll
        for (int g = 0; g < 2; ++g)
#pragma unroll
            for (int sh = 0; sh < 4; ++sh) sc[g][sh] = (f32x4){0.f, 0.f, 0.f, 0.f};
#pragma unroll
        for (int sh = 0; sh < 4; ++sh) {
            const bf16* qr = qb + (size_t)(s0 + sh * 16 + lo) * 3072;
            bf16x8 aQ0 = *(const bf16x8*)(qr + hi * 8);
            bf16x8 aQ1 = *(const bf16x8*)(qr + 32 + hi * 8);
#pragma unroll
            for (int g = 0; g < 2; ++g) {
                sc[g][sh] = __builtin_amdgcn_mfma_f32_16x16x32_bf16(aQ0, bK[g][0], sc[g][sh], 0, 0, 0);
                sc[g][sh] = __builtin_amdgcn_mfma_f32_16x16x32_bf16(aQ1, bK[g][1], sc[g][sh], 0, 0, 0);
            }
        }
        // V loads issued EARLY: latency hides under the softmax VALU below.
        bf16x8 bV0[4], bV1[4];
#pragma unroll
        for (int n = 0; n < 4; ++n) {
            bV0[n] = *(const bf16x8*)(vb + (size_t)(n * 16 + lo) * SEQ + s0 + hi * 8);
            bV1[n] = *(const bf16x8*)(vb + (size_t)(n * 16 + lo) * SEQ + s0 + 32 + hi * 8);
        }
        // softmax in exp2 domain
        float p[2][16], mx[2];
#pragma unroll
        for (int g = 0; g < 2; ++g) {
            const int tt = t0 + g * 16 + lo;
            mx[g] = -1e30f;
#pragma unroll
            for (int sh = 0; sh < 4; ++sh)
#pragma unroll
                for (int j = 0; j < 4; ++j) {
                    float val = sc[g][sh][j] * SC2;
                    if (masked) {
                        int s = s0 + sh * 16 + hi * 4 + j;
                        if (s > tt) val = -1e30f;
                    }
                    p[g][sh * 4 + j] = val;
                    mx[g] = fmaxf(mx[g], val);
                }
            mx[g] = fmaxf(mx[g], __shfl_xor(mx[g], 16));
            mx[g] = fmaxf(mx[g], __shfl_xor(mx[g], 32));
        }
        // defer-max (T13), shared trigger, log2 domain (bound 2^8)
        if (__any(fmaxf(mx[0] - mrun[0], mx[1] - mrun[1]) > 8.f)) {
#pragma unroll
            for (int g = 0; g < 2; ++g) {
                float mnew = fmaxf(mrun[g], mx[g]);
                float scl = exp2f(mrun[g] - mnew);
                mrun[g] = mnew;
                lrun[g] *= scl;
                float sclj[4];
#pragma unroll
                for (int j = 0; j < 4; ++j) sclj[j] = __shfl(scl, hi * 4 + j);
#pragma unroll
                for (int n = 0; n < 4; ++n)
#pragma unroll
                    for (int j = 0; j < 4; ++j)
                        o[g][n][j] *= sclj[j];
            }
        }
#pragma unroll
        for (int g = 0; g < 2; ++g) {
            float rs = 0.f;
#pragma unroll
            for (int i = 0; i < 16; ++i) { p[g][i] = exp2f(p[g][i] - mrun[g]); rs += p[g][i]; }
            rs += __shfl_xor(rs, 16);
            rs += __shfl_xor(rs, 32);
            lrun[g] += rs;
        }
        // publish P (same-wave DS ordering; no barrier needed in 1-wave block)
#pragma unroll
        for (int g = 0; g < 2; ++g)
#pragma unroll
            for (int sh = 0; sh < 4; ++sh) {
                bf16x4 w;
                w.x = (bf16)p[g][sh * 4 + 0]; w.y = (bf16)p[g][sh * 4 + 1];
                w.z = (bf16)p[g][sh * 4 + 2]; w.w = (bf16)p[g][sh * 4 + 3];
                *(bf16x4*)(&plds[g * 16 + lo][sh * 16 + hi * 4]) = w;
            }
        bf16x8 aP[2][2];
#pragma unroll
        for (int g = 0; g < 2; ++g) {
            aP[g][0] = *(const bf16x8*)(&plds[g * 16 + lo][hi * 8]);
            aP[g][1] = *(const bf16x8*)(&plds[g * 16 + lo][32 + hi * 8]);
        }
#pragma unroll
        for (int n = 0; n < 4; ++n)
#pragma unroll
            for (int g = 0; g < 2; ++g) {
                o[g][n] = __builtin_amdgcn_mfma_f32_16x16x32_bf16(aP[g][0], bV0[n], o[g][n], 0, 0, 0);
                o[g][n] = __builtin_amdgcn_mfma_f32_16x16x32_bf16(aP[g][1], bV1[n], o[g][n], 0, 0, 0);
            }
    };

    for (int it = 0; it < nfull; ++it) tile_body(it * 64, false);
    for (int it = nfull; it < nt; ++it) tile_body(it * 64, true);

#pragma unroll
    for (int g = 0; g < 2; ++g) {
        float lj[4];
#pragma unroll
        for (int j = 0; j < 4; ++j) lj[j] = __shfl(lrun[g], hi * 4 + j);
#pragma unroll
        for (int j = 0; j < 4; ++j) {
            float inv = 1.f / lj[j];
            size_t rowoff = (size_t)(b * SEQ + t0 + g * 16 + hi * 4 + j) * EMB + h * 64;
#pragma unroll
            for (int n = 0; n < 4; ++n)
                att[rowoff + n * 16 + lo] = (bf16)(o[g][n][j] * inv);
        }
    }
}

// ---------------------------------------------------------------------------
extern "C" void kernel_launch(void* const* d_in, const int* in_sizes, int n_in,
                              void* d_out, int out_size, void* d_ws, size_t ws_size,
                              hipStream_t stream)
{
    const int*   idx  = (const int*)d_in[0];
    const float* tok  = (const float*)d_in[1];
    const float* pos  = (const float*)d_in[2];
    const float* Wq   = (const float*)d_in[3];
    const float* Wk   = (const float*)d_in[4];
    const float* Wv   = (const float*)d_in[5];
    const float* Wo   = (const float*)d_in[6];
    const float* bo   = (const float*)d_in[7];
    const float* W1   = (const float*)d_in[8];
    const float* b1   = (const float*)d_in[9];
    const float* W2   = (const float*)d_in[10];
    const float* b2   = (const float*)d_in[11];
    const float* ln1g = (const float*)d_in[12];
    const float* ln1b = (const float*)d_in[13];
    const float* ln2g = (const float*)d_in[14];
    const float* ln2b = (const float*)d_in[15];
    const float* lnfg = (const float*)d_in[16];
    const float* lnfb = (const float*)d_in[17];
    const float* Wlm  = (const float*)d_in[18];
    const float* blm  = (const float*)d_in[19];
    float* out = (float*)d_out;

    char* ws = (char*)d_ws;
    size_t off = 0;
    auto alloc = [&](size_t bytes) { void* p = ws + off; off += (bytes + 255) & ~(size_t)255; return p; };
    bf16* x     = (bf16*)alloc((size_t)ROWS * EMB * 2);      // bf16 residual stream
    bf16* h     = (bf16*)alloc((size_t)ROWS * EMB * 2);
    bf16* qkv   = (bf16*)alloc((size_t)ROWS * 3072 * 2);
    bf16* vt    = (bf16*)alloc((size_t)ROWS * EMB * 2);
    bf16* attb  = (bf16*)alloc((size_t)ROWS * EMB * 2);
    bf16* mlp   = (bf16*)alloc((size_t)ROWS * 4096 * 2);
    bf16* WTqkv = (bf16*)alloc((size_t)3072 * 1024 * 2);
    bf16* WTo   = (bf16*)alloc((size_t)1024 * 1024 * 2);
    bf16* WT1   = (bf16*)alloc((size_t)4096 * 1024 * 2);
    bf16* WT2   = (bf16*)alloc((size_t)1024 * 4096 * 2);
    bf16* WTlm  = (bf16*)alloc((size_t)VOCAB * 1024 * 2);

    dim3 tb(32, 8);

    // LM head weight transpose (layer-independent)
    transpose_cvt<<<dim3(VOCAB / 32, 32), tb, 0, stream>>>(Wlm, WTlm, 1024, VOCAB);

    embed_kernel<<<ROWS, 256, 0, stream>>>(idx, tok, pos, x);

    for (int l = 0; l < LAYERS; ++l) {
        const size_t wqs = (size_t)l * 1024 * 1024;
        const size_t w14 = (size_t)l * 4096 * 1024;
        transpose_all<<<12288, tb, 0, stream>>>(
            Wq + wqs, Wk + wqs, Wv + wqs, Wo + wqs, W1 + w14, W2 + w14,
            WTqkv, WTqkv + (size_t)1024 * 1024, WTqkv + (size_t)2048 * 1024, WTo,
            WT1, WT2);

        ln_kernel<<<ROWS, 256, 0, stream>>>(x, ln1g + l * EMB, ln1b + l * EMB, h);
        gemm_kernel<4><<<dim3(24, 32), 256, 0, stream>>>(h, WTqkv, qkv, nullptr, nullptr, vt, 3072, 1024);
        attn_kernel<<<dim3(64, 32), 64, 0, stream>>>(qkv, vt, attb);
        gemm64_kernel<1><<<dim3(8, 64), 256, 0, stream>>>(attb, WTo, x, bo + l * EMB, x, 1024, 1024);
        ln_kernel<<<ROWS, 256, 0, stream>>>(x, ln2g + l * EMB, ln2b + l * EMB, h);
        gemm256_kernel<2><<<16 * 16, 512, 0, stream>>>(h, WT1, mlp, b1 + l * 4096, 4096, 1024, 16, 16);
        gemm64_kernel<1><<<dim3(8, 64), 256, 0, stream>>>(mlp, WT2, x, b2 + l * EMB, x, 1024, 4096);
    }
    ln_kernel<<<ROWS, 256, 0, stream>>>(x, lnfg, lnfb, h);
    gemm256_kernel<3><<<16 * 125, 512, 0, stream>>>(h, WTlm, out, blm, 32000, 1024, 16, 125);
}